// Round 4
// baseline (408.228 us; speedup 1.0000x reference)
//
#include <hip/hip_runtime.h>
#include <hip/hip_cooperative_groups.h>
#include <stdint.h>

#define NROWS 1024
#define NCOLS 16384
#define NBLK  256
#define NTHR  256
#define MAXR  1026   // round counters: >= max rounds + 1 (>=1 commit/round)

typedef unsigned long long u64;
typedef unsigned int u32;

namespace cg = cooperative_groups;

// Persistent device state (re-initialized every launch inside the kernel).
__device__ u64 g_rowbest[NROWS];    // key: (sortable_val<<32) | (NCOLS-1-col)
__device__ u64 g_colbest[NCOLS];    // key: (sortable_val<<32) | (NROWS-1-row)
__device__ int g_col_used[NCOLS];
__device__ int g_row_assigned[NROWS];
__device__ int g_rem[2][NROWS];     // double-buffered remaining-row lists
__device__ int g_cnt[MAXR];         // per-round list counters (pre-zeroed)
__device__ int g_nrem_fb;           // fallback path only

// Monotone float32 -> uint32 mapping (preserves <):
__device__ __forceinline__ u32 fsort(float x) {
    u32 u = __float_as_uint(x);
    return u ^ ((u32)((int)u >> 31) | 0x80000000u);
}

__device__ __forceinline__ u64 block_reduce_max(u64 v, u64* s_part) {
    for (int off = 32; off; off >>= 1) {
        u64 o = __shfl_down(v, off);
        if (o > v) v = o;
    }
    int wave = threadIdx.x >> 6;
    if ((threadIdx.x & 63) == 0) s_part[wave] = v;
    __syncthreads();
    u64 b = s_part[0];
    for (int w = 1; w < NTHR / 64; w++) if (s_part[w] > b) b = s_part[w];
    __syncthreads();   // make s_part reusable
    return b;          // valid in all threads
}

// ---------------- single cooperative kernel: the whole algorithm ------------
__global__ void __launch_bounds__(NTHR) k_lsa(const float* __restrict__ cost,
                                              int* __restrict__ out) {
    cg::grid_group grid = cg::this_grid();
    __shared__ u64 s_part[NTHR / 64];
    const int tid = threadIdx.x;
    const int b = blockIdx.x;
    const int gtid = b * NTHR + tid;

    // ---- Phase 0: init (no deps on other phases yet) ----
    for (int i = gtid; i < NCOLS; i += NBLK * NTHR) { g_colbest[i] = 0ULL; g_col_used[i] = 0; }
    if (gtid < NROWS) { g_row_assigned[gtid] = 0; out[gtid] = gtid; }
    if (gtid < MAXR) g_cnt[gtid] = 0;

    // ---- Phase 1: row maxima. Block b owns rows 4b..4b+3. ----
    for (int ri = 0; ri < 4; ri++) {
        int r = b * 4 + ri;
        const float4* row = (const float4*)(cost + (size_t)r * NCOLS);
        u64 best = 0ULL;
        for (int k = tid; k < NCOLS / 4; k += NTHR) {
            float4 v = row[k];
            int c0 = k * 4;
            u64 k0 = ((u64)fsort(v.x) << 32) | (u32)(NCOLS - 1 - (c0 + 0));
            u64 k1 = ((u64)fsort(v.y) << 32) | (u32)(NCOLS - 1 - (c0 + 1));
            u64 k2 = ((u64)fsort(v.z) << 32) | (u32)(NCOLS - 1 - (c0 + 2));
            u64 k3 = ((u64)fsort(v.w) << 32) | (u32)(NCOLS - 1 - (c0 + 3));
            if (k0 > best) best = k0;
            if (k1 > best) best = k1;
            if (k2 > best) best = k2;
            if (k3 > best) best = k3;
        }
        u64 bb = block_reduce_max(best, s_part);
        if (tid == 0) g_rowbest[r] = bb;
    }
    __threadfence();
    grid.sync();   // colbest zeroing visible before atomics

    // ---- Phase 2: col maxima. Block b -> tile (b&15)*1024 cols, (b>>4)*64 rows. ----
    {
        int c0 = (b & 15) * 1024 + tid * 4;
        int r0 = (b >> 4) * 64;
        u64 b0 = 0, b1 = 0, b2 = 0, b3 = 0;
        for (int r = r0; r < r0 + 64; ++r) {
            float4 v = *(const float4*)(cost + (size_t)r * NCOLS + c0);
            u32 rk = (u32)(NROWS - 1 - r);
            u64 k0 = ((u64)fsort(v.x) << 32) | rk;
            u64 k1 = ((u64)fsort(v.y) << 32) | rk;
            u64 k2 = ((u64)fsort(v.z) << 32) | rk;
            u64 k3 = ((u64)fsort(v.w) << 32) | rk;
            if (k0 > b0) b0 = k0;
            if (k1 > b1) b1 = k1;
            if (k2 > b2) b2 = k2;
            if (k3 > b3) b3 = k3;
        }
        atomicMax(&g_colbest[c0 + 0], b0);
        atomicMax(&g_colbest[c0 + 1], b1);
        atomicMax(&g_colbest[c0 + 2], b2);
        atomicMax(&g_colbest[c0 + 3], b3);
    }
    __threadfence();
    grid.sync();

    // ---- Phase 3: round-0 commit of mutual-best pairs (own rows). ----
    if (tid < 4) {
        int r = b * 4 + tid;
        u64 key = g_rowbest[r];
        int c = NCOLS - 1 - (int)(key & 0xFFFFFFFFu);
        u64 mk = (key & 0xFFFFFFFF00000000ULL) | (u32)(NROWS - 1 - r);
        if (g_colbest[c] == mk) {
            g_col_used[c] = 1;
            g_row_assigned[r] = 1;
            out[NROWS + r] = c;
        } else {
            int p = atomicAdd(&g_cnt[0], 1);
            g_rem[0][p] = r;
        }
    }
    __threadfence();
    grid.sync();

    // ---- Phase 4: rounds, one grid.sync each. ----
    int t = 0;
    while (t < MAXR - 1) {
        int n = g_cnt[t];          // identical in all blocks (post-sync)
        if (n == 0) break;
        const int* list = g_rem[t & 1];

        // (A) recompute own stale rows (cached best col was taken).
        for (int ri = 0; ri < 4; ri++) {
            int r = b * 4 + ri;
            if (g_row_assigned[r]) continue;                       // block-uniform
            u64 key = g_rowbest[r];
            int cb = NCOLS - 1 - (int)(key & 0xFFFFFFFFu);
            if (!g_col_used[cb]) continue;                         // cache valid
            u64 best = 0ULL;
            const float4* row = (const float4*)(cost + (size_t)r * NCOLS);
            const int4* used = (const int4*)g_col_used;
            for (int k = tid; k < NCOLS / 4; k += NTHR) {
                float4 v = row[k];
                int4 u = used[k];
                int c0 = k * 4;
                if (!u.x) { u64 kk = ((u64)fsort(v.x) << 32) | (u32)(NCOLS - 1 - (c0 + 0)); if (kk > best) best = kk; }
                if (!u.y) { u64 kk = ((u64)fsort(v.y) << 32) | (u32)(NCOLS - 1 - (c0 + 1)); if (kk > best) best = kk; }
                if (!u.z) { u64 kk = ((u64)fsort(v.z) << 32) | (u32)(NCOLS - 1 - (c0 + 2)); if (kk > best) best = kk; }
                if (!u.w) { u64 kk = ((u64)fsort(v.w) << 32) | (u32)(NCOLS - 1 - (c0 + 3)); if (kk > best) best = kk; }
            }
            u64 bb = block_reduce_max(best, s_part);
            if (tid == 0) g_rowbest[r] = bb;
            __syncthreads();
        }

        // (B) winner check for own unassigned rows: mine > every other listed
        // row's fresh value at my col  ->  mutual best -> commit.
        for (int ri = 0; ri < 4; ri++) {
            int r = b * 4 + ri;
            if (g_row_assigned[r]) continue;                       // block-uniform
            u64 key = g_rowbest[r];
            int c = NCOLS - 1 - (int)(key & 0xFFFFFFFFu);
            u64 mine = (key & 0xFFFFFFFF00000000ULL) | (u32)(NROWS - 1 - r);
            u64 mx = 0ULL;
            for (int j = tid; j < n; j += NTHR) {
                int rj = list[j];
                if (rj != r) {
                    float x = cost[(size_t)rj * NCOLS + c];
                    u64 kj = ((u64)fsort(x) << 32) | (u32)(NROWS - 1 - rj);
                    if (kj > mx) mx = kj;
                }
            }
            mx = block_reduce_max(mx, s_part);
            if (tid == 0) {
                if (mine > mx) {                                   // keys unique
                    g_col_used[c] = 1;
                    g_row_assigned[r] = 1;
                    out[NROWS + r] = c;
                } else {
                    int p = atomicAdd(&g_cnt[t + 1], 1);
                    g_rem[(t + 1) & 1][p] = r;
                }
            }
            __syncthreads();
        }
        __threadfence();
        grid.sync();
        t++;
    }
}

// ---------------- fallback path (only if cooperative launch errors) ---------
__global__ void k_init_fb(int* __restrict__ out) {
    int i = blockIdx.x * blockDim.x + threadIdx.x;
    if (i < NCOLS) { g_colbest[i] = 0ULL; g_col_used[i] = 0; }
    if (i < NROWS) { g_row_assigned[i] = 0; out[i] = i; }
    if (i < MAXR) g_cnt[i] = 0;
    if (i == 0) g_nrem_fb = 0;
}

__global__ void k_rowmax_fb(const float* __restrict__ cost) {
    int r = blockIdx.x;
    const float4* row = (const float4*)(cost + (size_t)r * NCOLS);
    u64 best = 0ULL;
    for (int k = threadIdx.x; k < NCOLS / 4; k += blockDim.x) {
        float4 v = row[k];
        int c0 = k * 4;
        u64 k0 = ((u64)fsort(v.x) << 32) | (u32)(NCOLS - 1 - (c0 + 0));
        u64 k1 = ((u64)fsort(v.y) << 32) | (u32)(NCOLS - 1 - (c0 + 1));
        u64 k2 = ((u64)fsort(v.z) << 32) | (u32)(NCOLS - 1 - (c0 + 2));
        u64 k3 = ((u64)fsort(v.w) << 32) | (u32)(NCOLS - 1 - (c0 + 3));
        if (k0 > best) best = k0;
        if (k1 > best) best = k1;
        if (k2 > best) best = k2;
        if (k3 > best) best = k3;
    }
    __shared__ u64 s_part[NTHR / 64];
    u64 bb = block_reduce_max(best, s_part);
    if (threadIdx.x == 0) g_rowbest[r] = bb;
}

__global__ void k_colmax_fb(const float* __restrict__ cost) {
    int c0 = blockIdx.x * 1024 + threadIdx.x * 4;
    int r0 = blockIdx.y * 64;
    u64 b0 = 0, b1 = 0, b2 = 0, b3 = 0;
    for (int r = r0; r < r0 + 64; ++r) {
        float4 v = *(const float4*)(cost + (size_t)r * NCOLS + c0);
        u32 rk = (u32)(NROWS - 1 - r);
        u64 k0 = ((u64)fsort(v.x) << 32) | rk;
        u64 k1 = ((u64)fsort(v.y) << 32) | rk;
        u64 k2 = ((u64)fsort(v.z) << 32) | rk;
        u64 k3 = ((u64)fsort(v.w) << 32) | rk;
        if (k0 > b0) b0 = k0;
        if (k1 > b1) b1 = k1;
        if (k2 > b2) b2 = k2;
        if (k3 > b3) b3 = k3;
    }
    atomicMax(&g_colbest[c0 + 0], b0);
    atomicMax(&g_colbest[c0 + 1], b1);
    atomicMax(&g_colbest[c0 + 2], b2);
    atomicMax(&g_colbest[c0 + 3], b3);
}

__global__ void k_commit1_fb(int* __restrict__ out) {
    int r = threadIdx.x;
    u64 key = g_rowbest[r];
    int c = NCOLS - 1 - (int)(key & 0xFFFFFFFFu);
    u64 mk = (key & 0xFFFFFFFF00000000ULL) | (u32)(NROWS - 1 - r);
    if (g_colbest[c] == mk) {
        g_col_used[c] = 1; g_row_assigned[r] = 1; out[NROWS + r] = c;
    } else {
        int p = atomicAdd(&g_nrem_fb, 1);
        g_rem[0][p] = r;
    }
}

// Persistent single-block finish (correct for any input, slow path).
__global__ void k_finish_fb(const float* __restrict__ cost, int* __restrict__ out) {
    __shared__ int s_rem[2][NROWS];
    __shared__ int s_n, s_newn;
    __shared__ u64 s_part2[16];
    int tid = threadIdx.x;
    if (tid == 0) s_n = g_nrem_fb;
    __syncthreads();
    int n = s_n;
    if (n == 0) return;
    for (int i = tid; i < n; i += blockDim.x) s_rem[0][i] = g_rem[0][i];
    __syncthreads();
    int cur = 0;
    while (n > 0) {
        for (int i = 0; i < n; i++) {
            int r = s_rem[cur][i];
            u64 key = g_rowbest[r];
            int c = NCOLS - 1 - (int)(key & 0xFFFFFFFFu);
            if (g_col_used[c]) {
                u64 best = 0ULL;
                const float4* row = (const float4*)(cost + (size_t)r * NCOLS);
                for (int k = tid; k < NCOLS / 4; k += blockDim.x) {
                    float4 v = row[k];
                    int c0 = k * 4;
                    if (!g_col_used[c0 + 0]) { u64 kk = ((u64)fsort(v.x) << 32) | (u32)(NCOLS - 1 - (c0 + 0)); if (kk > best) best = kk; }
                    if (!g_col_used[c0 + 1]) { u64 kk = ((u64)fsort(v.y) << 32) | (u32)(NCOLS - 1 - (c0 + 1)); if (kk > best) best = kk; }
                    if (!g_col_used[c0 + 2]) { u64 kk = ((u64)fsort(v.z) << 32) | (u32)(NCOLS - 1 - (c0 + 2)); if (kk > best) best = kk; }
                    if (!g_col_used[c0 + 3]) { u64 kk = ((u64)fsort(v.w) << 32) | (u32)(NCOLS - 1 - (c0 + 3)); if (kk > best) best = kk; }
                }
                for (int off = 32; off; off >>= 1) {
                    u64 o = __shfl_down(best, off);
                    if (o > best) best = o;
                }
                int wave = tid >> 6;
                if ((tid & 63) == 0) s_part2[wave] = best;
                __syncthreads();
                if (tid == 0) {
                    u64 b = s_part2[0];
                    for (int w = 1; w < 16; w++) if (s_part2[w] > b) b = s_part2[w];
                    g_rowbest[r] = b;
                }
                __syncthreads();
            }
        }
        __syncthreads();
        bool win = false; int myr = -1, myc = -1;
        if (tid < n) {
            int r = s_rem[cur][tid];
            u64 key = g_rowbest[r];
            int c = NCOLS - 1 - (int)(key & 0xFFFFFFFFu);
            u64 mine = (key & 0xFFFFFFFF00000000ULL) | (u32)(NROWS - 1 - r);
            win = true;
            for (int j = 0; j < n; j++) {
                int rj = s_rem[cur][j];
                if (rj == r) continue;
                float x = cost[(size_t)rj * NCOLS + c];
                u64 kj = ((u64)fsort(x) << 32) | (u32)(NROWS - 1 - rj);
                if (kj > mine) { win = false; break; }
            }
            myr = r; myc = c;
        }
        __syncthreads();
        if (win) {
            g_col_used[myc] = 1; g_row_assigned[myr] = 1; out[NROWS + myr] = myc;
        }
        if (tid == 0) s_newn = 0;
        __syncthreads();
        if (tid < n && !win) {
            int p = atomicAdd(&s_newn, 1);
            s_rem[cur ^ 1][p] = myr;
        }
        __syncthreads();
        n = s_newn;
        cur ^= 1;
        __syncthreads();
    }
}

extern "C" void kernel_launch(void* const* d_in, const int* in_sizes, int n_in,
                              void* d_out, int out_size, void* d_ws, size_t ws_size,
                              hipStream_t stream) {
    const float* cost = (const float*)d_in[0];
    int* out = (int*)d_out;

    void* args[] = { (void*)&cost, (void*)&out };
    hipError_t err = hipLaunchCooperativeKernel((const void*)k_lsa,
                                                dim3(NBLK), dim3(NTHR),
                                                args, 0, stream);
    if (err != hipSuccess) {
        // Deterministic fallback: multi-kernel path (same algorithm).
        k_init_fb<<<NCOLS / 256, 256, 0, stream>>>(out);
        k_rowmax_fb<<<NROWS, NTHR, 0, stream>>>(cost);
        k_colmax_fb<<<dim3(NCOLS / 1024, NROWS / 64), 256, 0, stream>>>(cost);
        k_commit1_fb<<<1, 1024, 0, stream>>>(out);
        k_finish_fb<<<1, 1024, 0, stream>>>(cost, out);
    }
}

// Round 5
// 162.478 us; speedup vs baseline: 2.5125x; 2.5125x over previous
//
#include <hip/hip_runtime.h>
#include <stdint.h>

#define NROWS 1024
#define NCOLS 16384
#define NRB 16        // row tiles (64 rows each)
#define NCB 16        // col tiles (1024 cols each)
#define NROUNDS 3

typedef unsigned long long u64;
typedef unsigned int u32;

// Persistent device state. Everything is plain-written each call before being
// read (no reliance on prior-call state): partials are overwritten by k_scan;
// col_used/cnt/assigned/rowbest are (re)written by k_commit1.
__device__ u64 g_rowpart[NCB * NROWS];   // per col-tile row maxima
__device__ u64 g_colpart[NRB * NCOLS];   // per row-tile col maxima
__device__ u64 g_rowbest[NROWS];         // key: (sortable<<32) | (NCOLS-1-col)
__device__ int g_col_used[NCOLS];
__device__ int g_row_assigned[NROWS];
__device__ int g_rem[2][NROWS];          // double-buffered remaining lists
__device__ int g_cnt[NROUNDS + 1];       // list counts per round

// Monotone float32 -> uint32 mapping (preserves <):
__device__ __forceinline__ u32 fsort(float x) {
    u32 u = __float_as_uint(x);
    return u ^ ((u32)((int)u >> 31) | 0x80000000u);
}

__device__ __forceinline__ u64 block_reduce_max(u64 v, u64* s_part) {
    for (int off = 32; off; off >>= 1) {
        u64 o = __shfl_down(v, off);
        if (o > v) v = o;
    }
    int wave = threadIdx.x >> 6;
    if ((threadIdx.x & 63) == 0) s_part[wave] = v;
    __syncthreads();
    u64 b = s_part[0];
    for (int w = 1; w < 4; w++) if (s_part[w] > b) b = s_part[w];
    __syncthreads();
    return b;
}

// One pass over the matrix: grid (NCB, NRB), block 256. Tile = 64 rows x 1024
// cols. Writes col partials (plain stores) and row partials (wave-per-row
// reduce, tile re-read from L2). No atomics -> no init kernel needed.
__global__ void __launch_bounds__(256) k_scan(const float* __restrict__ cost) {
    const int tid = threadIdx.x;
    const int cb = blockIdx.x, rb = blockIdx.y;
    const int cbase = cb * 1024;
    const int r0 = rb * 64;

    // Pass 1: column maxima over the 64 rows (coalesced float4, ties->smaller row).
    int c0 = cbase + tid * 4;
    u64 b0 = 0, b1 = 0, b2 = 0, b3 = 0;
    for (int r = r0; r < r0 + 64; ++r) {
        float4 v = *(const float4*)(cost + (size_t)r * NCOLS + c0);
        u32 rk = (u32)(NROWS - 1 - r);
        u64 k0 = ((u64)fsort(v.x) << 32) | rk;
        u64 k1 = ((u64)fsort(v.y) << 32) | rk;
        u64 k2 = ((u64)fsort(v.z) << 32) | rk;
        u64 k3 = ((u64)fsort(v.w) << 32) | rk;
        if (k0 > b0) b0 = k0;
        if (k1 > b1) b1 = k1;
        if (k2 > b2) b2 = k2;
        if (k3 > b3) b3 = k3;
    }
    size_t cp = (size_t)rb * NCOLS + c0;
    g_colpart[cp + 0] = b0;
    g_colpart[cp + 1] = b1;
    g_colpart[cp + 2] = b2;
    g_colpart[cp + 3] = b3;

    // Pass 2: row maxima. Wave w handles 16 rows; 64 lanes x 4 float4 cover
    // the 1024-col strip (tile is L2-resident from pass 1).
    int wv = tid >> 6, lane = tid & 63;
    for (int i = 0; i < 16; i++) {
        int r = r0 + wv * 16 + i;
        const float* rowp = cost + (size_t)r * NCOLS;
        u64 m = 0ULL;
        for (int s = 0; s < 4; s++) {
            int c = cbase + s * 256 + lane * 4;
            float4 v = *(const float4*)(rowp + c);
            u64 k0 = ((u64)fsort(v.x) << 32) | (u32)(NCOLS - 1 - (c + 0));
            u64 k1 = ((u64)fsort(v.y) << 32) | (u32)(NCOLS - 1 - (c + 1));
            u64 k2 = ((u64)fsort(v.z) << 32) | (u32)(NCOLS - 1 - (c + 2));
            u64 k3 = ((u64)fsort(v.w) << 32) | (u32)(NCOLS - 1 - (c + 3));
            if (k0 > m) m = k0;
            if (k1 > m) m = k1;
            if (k2 > m) m = k2;
            if (k3 > m) m = k3;
        }
        for (int off = 32; off; off >>= 1) {
            u64 o = __shfl_down(m, off);
            if (o > m) m = o;
        }
        if (lane == 0) g_rowpart[cb * NROWS + r] = m;
    }
}

// 1 block, 1024 threads: combine partials, commit round-0 mutual-best pairs,
// init col_used / counters / identity output.
__global__ void __launch_bounds__(1024) k_commit1(int* __restrict__ out) {
    int r = threadIdx.x;
    for (int i = r; i < NCOLS; i += 1024) g_col_used[i] = 0;
    if (r <= NROUNDS) g_cnt[r] = 0;
    out[r] = r;                       // rows sorted ascending = identity
    __syncthreads();

    u64 key = 0ULL;
    for (int cb = 0; cb < NCB; cb++) {
        u64 v = g_rowpart[cb * NROWS + r];
        if (v > key) key = v;
    }
    g_rowbest[r] = key;
    int c = NCOLS - 1 - (int)(key & 0xFFFFFFFFu);
    u64 colmax = 0ULL;
    for (int rb = 0; rb < NRB; rb++) {
        u64 v = g_colpart[(size_t)rb * NCOLS + c];
        if (v > colmax) colmax = v;
    }
    u64 mk = (key & 0xFFFFFFFF00000000ULL) | (u32)(NROWS - 1 - r);
    if (colmax == mk) {               // mutual best -> greedy-correct commit
        g_col_used[c] = 1;
        g_row_assigned[r] = 1;
        out[NROWS + r] = c;
    } else {
        g_row_assigned[r] = 0;
        int p = atomicAdd(&g_cnt[0], 1);
        g_rem[0][p] = r;
    }
}

// Fused per-round kernel: block r = row r. Assigned rows exit instantly.
// (a) rescan own row if cached best col was taken; (b) winner check against
// raw cost values of all rows remaining at round start. Within-round
// col_used races are benign: every used col is a valid commit, the winner
// per col is unique, and losers simply retry next round.
__global__ void __launch_bounds__(256) k_round(const float* __restrict__ cost,
                                               int* __restrict__ out, int t) {
    int r = blockIdx.x;
    if (g_row_assigned[r]) return;
    int tid = threadIdx.x;
    __shared__ u64 s_part[4];

    u64 key = g_rowbest[r];
    int c = NCOLS - 1 - (int)(key & 0xFFFFFFFFu);
    if (g_col_used[c]) {              // stale -> rescan excluding used cols
        u64 best = 0ULL;
        const float4* row = (const float4*)(cost + (size_t)r * NCOLS);
        const int4* used = (const int4*)g_col_used;
        for (int k = tid; k < NCOLS / 4; k += 256) {
            float4 v = row[k];
            int4 u = used[k];
            int c0 = k * 4;
            if (!u.x) { u64 kk = ((u64)fsort(v.x) << 32) | (u32)(NCOLS - 1 - (c0 + 0)); if (kk > best) best = kk; }
            if (!u.y) { u64 kk = ((u64)fsort(v.y) << 32) | (u32)(NCOLS - 1 - (c0 + 1)); if (kk > best) best = kk; }
            if (!u.z) { u64 kk = ((u64)fsort(v.z) << 32) | (u32)(NCOLS - 1 - (c0 + 2)); if (kk > best) best = kk; }
            if (!u.w) { u64 kk = ((u64)fsort(v.w) << 32) | (u32)(NCOLS - 1 - (c0 + 3)); if (kk > best) best = kk; }
        }
        key = block_reduce_max(best, s_part);
        if (tid == 0) g_rowbest[r] = key;
        c = NCOLS - 1 - (int)(key & 0xFFFFFFFFu);
    }

    int n = g_cnt[t];
    const int* list = g_rem[t & 1];
    u64 mine = (key & 0xFFFFFFFF00000000ULL) | (u32)(NROWS - 1 - r);
    u64 mx = 0ULL;
    for (int j = tid; j < n; j += 256) {
        int rj = list[j];
        if (rj != r) {
            float x = cost[(size_t)rj * NCOLS + c];
            u64 kj = ((u64)fsort(x) << 32) | (u32)(NROWS - 1 - rj);
            if (kj > mx) mx = kj;
        }
    }
    mx = block_reduce_max(mx, s_part);
    if (tid == 0) {
        if (mine > mx) {              // unique max at col c among survivors
            g_col_used[c] = 1;
            g_row_assigned[r] = 1;
            out[NROWS + r] = c;
        } else {
            int p = atomicAdd(&g_cnt[t + 1], 1);
            g_rem[(t + 1) & 1][p] = r;
        }
    }
}

// Correctness fallback: persistent single-block loop (normally sees n==0 and
// exits immediately).
__global__ void __launch_bounds__(1024) k_finish(const float* __restrict__ cost,
                                                 int* __restrict__ out) {
    __shared__ int s_rem[2][NROWS];
    __shared__ int s_n, s_newn;
    __shared__ u64 s_part2[16];
    int tid = threadIdx.x;
    if (tid == 0) s_n = g_cnt[NROUNDS];
    __syncthreads();
    int n = s_n;
    if (n == 0) return;
    for (int i = tid; i < n; i += blockDim.x) s_rem[0][i] = g_rem[NROUNDS & 1][i];
    __syncthreads();
    int cur = 0;
    while (n > 0) {
        for (int i = 0; i < n; i++) {
            int r = s_rem[cur][i];
            u64 key = g_rowbest[r];
            int c = NCOLS - 1 - (int)(key & 0xFFFFFFFFu);
            if (g_col_used[c]) {
                u64 best = 0ULL;
                const float4* row = (const float4*)(cost + (size_t)r * NCOLS);
                for (int k = tid; k < NCOLS / 4; k += blockDim.x) {
                    float4 v = row[k];
                    int c0 = k * 4;
                    if (!g_col_used[c0 + 0]) { u64 kk = ((u64)fsort(v.x) << 32) | (u32)(NCOLS - 1 - (c0 + 0)); if (kk > best) best = kk; }
                    if (!g_col_used[c0 + 1]) { u64 kk = ((u64)fsort(v.y) << 32) | (u32)(NCOLS - 1 - (c0 + 1)); if (kk > best) best = kk; }
                    if (!g_col_used[c0 + 2]) { u64 kk = ((u64)fsort(v.z) << 32) | (u32)(NCOLS - 1 - (c0 + 2)); if (kk > best) best = kk; }
                    if (!g_col_used[c0 + 3]) { u64 kk = ((u64)fsort(v.w) << 32) | (u32)(NCOLS - 1 - (c0 + 3)); if (kk > best) best = kk; }
                }
                for (int off = 32; off; off >>= 1) {
                    u64 o = __shfl_down(best, off);
                    if (o > best) best = o;
                }
                int wave = tid >> 6;
                if ((tid & 63) == 0) s_part2[wave] = best;
                __syncthreads();
                if (tid == 0) {
                    u64 b = s_part2[0];
                    for (int w = 1; w < 16; w++) if (s_part2[w] > b) b = s_part2[w];
                    g_rowbest[r] = b;
                }
                __syncthreads();
            }
        }
        __syncthreads();
        bool win = false; int myr = -1, myc = -1;
        if (tid < n) {
            int r = s_rem[cur][tid];
            u64 key = g_rowbest[r];
            int c = NCOLS - 1 - (int)(key & 0xFFFFFFFFu);
            u64 mine = (key & 0xFFFFFFFF00000000ULL) | (u32)(NROWS - 1 - r);
            win = true;
            for (int j = 0; j < n; j++) {
                int rj = s_rem[cur][j];
                if (rj == r) continue;
                float x = cost[(size_t)rj * NCOLS + c];
                u64 kj = ((u64)fsort(x) << 32) | (u32)(NROWS - 1 - rj);
                if (kj > mine) { win = false; break; }
            }
            myr = r; myc = c;
        }
        __syncthreads();
        if (win) {
            g_col_used[myc] = 1; g_row_assigned[myr] = 1; out[NROWS + myr] = myc;
        }
        if (tid == 0) s_newn = 0;
        __syncthreads();
        if (tid < n && !win) {
            int p = atomicAdd(&s_newn, 1);
            s_rem[cur ^ 1][p] = myr;
        }
        __syncthreads();
        n = s_newn;
        cur ^= 1;
        __syncthreads();
    }
}

extern "C" void kernel_launch(void* const* d_in, const int* in_sizes, int n_in,
                              void* d_out, int out_size, void* d_ws, size_t ws_size,
                              hipStream_t stream) {
    const float* cost = (const float*)d_in[0];
    int* out = (int*)d_out;

    k_scan<<<dim3(NCB, NRB), 256, 0, stream>>>(cost);
    k_commit1<<<1, 1024, 0, stream>>>(out);
    for (int t = 0; t < NROUNDS; ++t)
        k_round<<<NROWS, 256, 0, stream>>>(cost, out, t);
    k_finish<<<1, 1024, 0, stream>>>(cost, out);
}